// Round 4
// baseline (273.151 us; speedup 1.0000x reference)
//
#include <hip/hip_runtime.h>
#include <hip/hip_fp16.h>
#include <cstddef>

#define Bc   32
#define Nc   512
#define Mc   512
#define DFc  64
#define BIGC 1.0e10f
#define LOG2E_F 1.4426950408889634f
#define LN2_F   0.6931471805599453f
#define SQRT_LOG2E_F 1.2011224087864498f

typedef unsigned int uint32;
typedef _Float16 f16x8 __attribute__((ext_vector_type(8)));
typedef float    f32x4 __attribute__((ext_vector_type(4)));

// per-tile ready flags: 32 batches x 4 strips x 4 J  (module-scope, not d_ws)
__device__ int g_flags[512];

__device__ __forceinline__ float dpp_shr1(float oldv, float src) {
    return __int_as_float(__builtin_amdgcn_update_dpp(
        __float_as_int(oldv), __float_as_int(src), 0x138, 0xf, 0xf, false));
}
__device__ __forceinline__ float dpp_shr1_nc(float src) {
    return __int_as_float(__builtin_amdgcn_mov_dpp(
        __float_as_int(src), 0x138, 0xf, 0xf, false));
}
__device__ __forceinline__ float rl(float v, int lane) {
    return __int_as_float(__builtin_amdgcn_readlane(__float_as_int(v), lane));
}

// Bit-trick softmin, log2 domain, minus 127 (bias pre-folded into Dsk).
__device__ __forceinline__ float softmin3m(float a, float b, float c) {
    float mn = fminf(fminf(a, b), c);
    float mx = fmaxf(fmaxf(a, b), c);
    float md = __builtin_amdgcn_fmed3f(a, b, c);
    uint32 b1 = (uint32)fmaf(mn - mx, 8388608.0f, 1065353216.0f);
    uint32 b2 = (uint32)fmaf(mn - md, 8388608.0f, 1065353216.0f);
    float E = 1.0f + (__int_as_float(b1) + __int_as_float(b2));
    return fmaf((float)__float_as_uint(E), -1.1920929e-7f, mn);
}

__device__ __forceinline__ void waitflag(int* f) {
    while (__hip_atomic_load(f, __ATOMIC_ACQUIRE, __HIP_MEMORY_SCOPE_AGENT) == 0) {
        __builtin_amdgcn_s_sleep(2);
    }
}

__global__ void init_kernel()
{
    g_flags[threadIdx.x] = 0;
}

// ---------------------------------------------------------------------------
// Fused kernel. Blocks 0..511: MFMA distance tile (b,strip,J) + flag release.
// Blocks 512..543: scan for batch bb = blockIdx.x - 512, acquire-polling the
// tile flag immediately before each tile prefetch. Scan SSTEP structure is
// the round-2 form verbatim (round-3's pair interleave reverted: it regressed
// 122 -> 150 us at equal VALU-busy).
// ---------------------------------------------------------------------------
#define SSTEP(T, dAw, dBw, PH1)                                            \
  {                                                                        \
    float2 fA = __half22float2(*(const __half2*)&(dAw));                   \
    float2 fB = __half22float2(*(const __half2*)&(dBw));                   \
    float u1, u2;                                                          \
    if (PH1) {                                                             \
      u1 = dpp_shr1(rl(Fodd, (T) - 1), pub1);                              \
      u2 = dpp_shr1(rl(Fev,  (T) - 1), curB);                              \
    } else {                                                               \
      u1 = dpp_shr1_nc(pub1);                                              \
      u2 = dpp_shr1_nc(curB);                                              \
    }                                                                      \
    float A1 = softmin3m(diagA, u1, curA) + fA.x;                          \
    float A2 = softmin3m(u1, u2, A1) + fA.y;                               \
    float B1 = softmin3m(curA, A1, curB) + fB.x;                           \
    float B2 = softmin3m(A1, A2, B1) + fB.y;                               \
    if ((T) == scap)                                                       \
      capv = useB ? (useC2 ? B2 : B1) : (useC2 ? A2 : A1);                 \
    bool act = (PH1) ? (l < (T)) : (l >= (T) - 64);                        \
    pub1  = act ? B1 : curB;   /* reads curB BEFORE update */              \
    curA  = act ? A2 : curA;                                               \
    curB  = act ? B2 : curB;                                               \
    diagA = u2;                                                            \
    if (!(PH1)) { wbase[2 * (T) - 127] = B1; wbase[2 * (T) - 126] = B2; }  \
  }

__global__ __launch_bounds__(256) void fused_kernel(
    const float* __restrict__ X, const float* __restrict__ Y,
    uint32* __restrict__ Dsk,
    const int* __restrict__ X_len, const int* __restrict__ Y_len,
    float* __restrict__ out)
{
    __shared__ __align__(16) unsigned char SMEM[35840];
    const int bi  = blockIdx.x;
    const int tid = threadIdx.x;

    if (bi < 512) {
        // ================= dist role =================
        unsigned short* XsH = (unsigned short*)SMEM;            // 16384 B
        unsigned short* YsH = (unsigned short*)(SMEM + 16384);  // 16384 B
        uint32* P  = (uint32*)SMEM;                             // 34816 B (aliases)
        float* xx2 = (float*)(SMEM + 34816);                    // 512 B
        float* yy2 = (float*)(SMEM + 35328);                    // 512 B

        const int J     = bi & 3;
        const int strip = (bi >> 2) & 3;
        const int b     = bi >> 4;

        const float* Xg = X + ((size_t)b * Nc + strip * 128) * DFc;
        const float* Yg = Y + ((size_t)b * Mc + J * 128) * DFc;

#pragma unroll
        for (int it = 0; it < 8; ++it) {
            int e4 = it * 256 + tid;
            int n = e4 >> 4, k4 = (e4 & 15) * 4;
            float4 v = ((const float4*)Xg)[e4];
            float sx = v.x * SQRT_LOG2E_F, sy = v.y * SQRT_LOG2E_F;
            float sz = v.z * SQRT_LOG2E_F, sw = v.w * SQRT_LOG2E_F;
            __half2 h01 = __floats2half2_rn(sx, sy);
            __half2 h23 = __floats2half2_rn(sz, sw);
            int ho = (k4 + 8 * (n & 7)) & 63;
            uint2 u; u.x = *(uint32*)&h01; u.y = *(uint32*)&h23;
            *(uint2*)&XsH[n * 64 + ho] = u;
            float p = sx * sx + sy * sy + sz * sz + sw * sw;
            p += __shfl_xor(p, 1);
            p += __shfl_xor(p, 2);
            p += __shfl_xor(p, 4);
            p += __shfl_xor(p, 8);
            if ((tid & 15) == 0) xx2[n] = p + 127.0f;   // fold +127 bias
        }
#pragma unroll
        for (int it = 0; it < 8; ++it) {
            int e4 = it * 256 + tid;
            int m = e4 >> 4, k4 = (e4 & 15) * 4;
            float4 v = ((const float4*)Yg)[e4];
            float sx = v.x * SQRT_LOG2E_F, sy = v.y * SQRT_LOG2E_F;
            float sz = v.z * SQRT_LOG2E_F, sw = v.w * SQRT_LOG2E_F;
            __half2 h01 = __floats2half2_rn(sx, sy);
            __half2 h23 = __floats2half2_rn(sz, sw);
            int ho = (k4 + 8 * (m & 7)) & 63;
            uint2 u; u.x = *(uint32*)&h01; u.y = *(uint32*)&h23;
            *(uint2*)&YsH[m * 64 + ho] = u;
            float p = sx * sx + sy * sy + sz * sz + sw * sw;
            p += __shfl_xor(p, 1);
            p += __shfl_xor(p, 2);
            p += __shfl_xor(p, 4);
            p += __shfl_xor(p, 8);
            if ((tid & 15) == 0) yy2[m] = p;
        }
        __syncthreads();

        const int l  = tid & 63;
        const int w  = tid >> 6;
        const int lr = l & 15;
        const int lk = l >> 4;

        f32x4 acc[2][8];
#pragma unroll
        for (int rt = 0; rt < 2; ++rt)
#pragma unroll
            for (int ct = 0; ct < 8; ++ct) {
                f32x4 z = {0.f, 0.f, 0.f, 0.f};
                acc[rt][ct] = z;
            }

#pragma unroll
        for (int ks = 0; ks < 2; ++ks) {
            f16x8 af[2], bf[8];
#pragma unroll
            for (int rt = 0; rt < 2; ++rt) {
                int row = w * 32 + rt * 16 + lr;
                int ho = (ks * 32 + lk * 8 + 8 * (row & 7)) & 63;
                af[rt] = *(const f16x8*)&XsH[row * 64 + ho];
            }
#pragma unroll
            for (int ct = 0; ct < 8; ++ct) {
                int col = ct * 16 + lr;
                int ho = (ks * 32 + lk * 8 + 8 * (col & 7)) & 63;
                bf[ct] = *(const f16x8*)&YsH[col * 64 + ho];
            }
#pragma unroll
            for (int rt = 0; rt < 2; ++rt)
#pragma unroll
                for (int ct = 0; ct < 8; ++ct)
                    acc[rt][ct] = __builtin_amdgcn_mfma_f32_16x16x32_f16(
                        af[rt], bf[ct], acc[rt][ct], 0, 0, 0);
        }
        __syncthreads();   // Xs/Ys dead; P may now overwrite them

#pragma unroll
        for (int rt = 0; rt < 2; ++rt) {
            int rbase = w * 32 + rt * 16 + 4 * lk;
            f32x4 xr = *(const f32x4*)&xx2[rbase];
            int p0 = rbase >> 1;
#pragma unroll
            for (int ct = 0; ct < 8; ++ct) {
                int c = ct * 16 + lr;
                float yv = yy2[c];
                f32x4 a = acc[rt][ct];
                float d0 = xr[0] + yv - 2.0f * a[0];
                float d1 = xr[1] + yv - 2.0f * a[1];
                float d2 = xr[2] + yv - 2.0f * a[2];
                float d3 = xr[3] + yv - 2.0f * a[3];
                __half2 h0 = __floats2half2_rn(d0, d1);
                __half2 h1 = __floats2half2_rn(d2, d3);
                P[c * 67 + p0]     = *(uint32*)&h0;
                P[c * 67 + p0 + 1] = *(uint32*)&h1;
            }
        }
        __syncthreads();

        const int q = tid >> 6;
        uint4* outt = (uint4*)Dsk + (((size_t)b * 4 + strip) * 4 + J) * 4096;
        const uint32* Pl = P + l;
#pragma unroll
        for (int gi = 0; gi < 16; ++gi) {
            int g = q + 4 * gi;
            int ka = 4 * g - 2 * l;
            int c0 = min(max(ka,     0), 127);
            int c1 = min(max(ka + 1, 0), 127);
            int c2 = min(max(ka + 2, 0), 127);
            int c3 = min(max(ka + 3, 0), 127);
            uint32 p0 = Pl[c0 * 67];
            uint32 p1 = Pl[c1 * 67];
            uint32 p2 = Pl[c2 * 67];
            uint32 p3 = Pl[c3 * 67];
            uint4 v;
            v.x = (p0 & 0xffffu) | (p1 << 16);
            v.y = (p0 >> 16)     | (p1 & 0xffff0000u);
            v.z = (p2 & 0xffffu) | (p3 << 16);
            v.w = (p2 >> 16)     | (p3 & 0xffff0000u);
            outt[g * 64 + l] = v;
        }

        // release: all threads fence their stores, then one release-store
        __threadfence();
        __syncthreads();
        if (tid == 0)
            __hip_atomic_store(&g_flags[(b * 4 + strip) * 4 + J], 1,
                               __ATOMIC_RELEASE, __HIP_MEMORY_SCOPE_AGENT);
        return;
    }

    // ================= scan role =================
    float* FrowP   = (float*)SMEM;            // 4 x 520 floats = 8320 B
    float* dumpP   = (float*)(SMEM + 8320);   // 136 floats

    const int l  = tid & 63;
    const int wl = __builtin_amdgcn_readfirstlane(tid >> 6);  // strip 0..3
    const int bb = bi - 512;

    const int xl = X_len[bb], yl = Y_len[bb];
    const int wxl  = (xl - 1) >> 7;           // capture strip
    const int iw   = (xl - 1) & 127;
    const int lcap = iw >> 1;                 // capture lane
    const int useB = iw & 1;                  // row parity (A/B)
    const int Jcap = (yl - 1) >> 7;           // capture tile (128-col)
    const int ycol = yl - (Jcap << 7);        // 1..128
    const int useC2 = 1 - (ycol & 1);         // even rel-col -> second cell
    const int tcap = ((ycol + 1) >> 1) + lcap;   // in [1,127]
    const int kmax = wxl + Jcap;              // <= 6

    const bool is63 = (l == 63);
    const int voff = l * 16;

    // wave-uniform byte base for this strip's tiles (J advances by 65536 B)
    const char* tbw = (const char*)Dsk +
        ((((size_t)bb * 4 + wl) * 4) * 4096) * 16;
    int* fbase = &g_flags[(bb * 4 + wl) * 4];

    if (l == 0) FrowP[wl * 520] = BIGC;       // col-0 border for f0 at J=0
    __syncthreads();

    float curA = BIGC, curB = BIGC, pub1 = BIGC;
    float diagA = BIGC;
    float capv = 0.0f;

    // prologue prefetch for tile J=0 (wait for its producer first)
    uint4 dreg[8];
    if (wl <= wxl) {
        waitflag(fbase);
#pragma unroll
        for (int q = 0; q < 8; ++q)
            dreg[q] = *(const uint4*)(tbw + voff + q * 1024);
    }

    for (int k = 0; k <= kmax; ++k) {
        int J = k - wl;
        if (wl <= wxl && 0 <= J && J <= Jcap) {
            const int j0 = J << 7;
            float Fodd, Fev, f0;
            if (wl > 0) {
                Fodd = FrowP[(wl - 1) * 520 + j0 + 1 + 2 * l];
                Fev  = FrowP[(wl - 1) * 520 + j0 + 2 + 2 * l];
                f0   = FrowP[(wl - 1) * 520 + j0];
            } else {
                Fodd = BIGC; Fev = BIGC;
                f0 = (J == 0) ? 0.0f : BIGC;           // R[0][0] = 0
            }
            diagA = (l == 0) ? f0 : diagA;

            const char* tb = tbw + (size_t)J * 65536;
            const int scap = (wl == wxl && J == Jcap) ? tcap : -1000;
            float* wbase = is63 ? (&FrowP[wl * 520 + j0]) : (dumpP + 4);
            const bool nextJ = (J < Jcap);

            // ---- phase 1: g 0..31 (t = 1..64): lane0 inject, no stores ----
#pragma unroll 1
            for (int m = 0; m < 4; ++m) {
#pragma unroll
                for (int q = 0; q < 8; ++q) {
                    const int g = m * 8 + q;
                    uint4 dc = dreg[q];
                    SSTEP(2 * g + 1, dc.x, dc.y, true)
                    SSTEP(2 * g + 2, dc.z, dc.w, true)
                    dreg[q] = *(const uint4*)(tb + voff + (g + 8) * 1024);
                }
            }
            // t=64 boundary publish: lane63 (just activated) cols 1,2
            wbase[1] = pub1;
            wbase[2] = curB;

            // ---- phase 2: g 32..55 (t = 65..112): no inject, store pair ----
#pragma unroll 1
            for (int m = 4; m < 7; ++m) {
#pragma unroll
                for (int q = 0; q < 8; ++q) {
                    const int g = m * 8 + q;
                    uint4 dc = dreg[q];
                    SSTEP(2 * g + 1, dc.x, dc.y, false)
                    SSTEP(2 * g + 2, dc.z, dc.w, false)
                    dreg[q] = *(const uint4*)(tb + voff + (g + 8) * 1024);
                }
            }
            // ---- peel: g 56..63 (t = 113..127; t=128 skipped).
            //      Wait for tile J+1's producer, then interleave its
            //      prologue prefetch. ----
            if (nextJ) waitflag(fbase + J + 1);
#pragma unroll
            for (int q = 0; q < 8; ++q) {
                const int g = 56 + q;
                uint4 dc = dreg[q];
                SSTEP(2 * g + 1, dc.x, dc.y, false)
                if (g < 63) { SSTEP(2 * g + 2, dc.z, dc.w, false) }
                if (nextJ)
                    dreg[q] = *(const uint4*)(tb + 65536 + voff + q * 1024);
            }
        }
        __syncthreads();
    }

    if (wl == wxl) {
        float o = rl(capv, lcap);
        if (l == 0) out[bb] = o * LN2_F;
    }
}

extern "C" void kernel_launch(void* const* d_in, const int* in_sizes, int n_in,
                              void* d_out, int out_size, void* d_ws, size_t ws_size,
                              hipStream_t stream)
{
    const float* X  = (const float*)d_in[0];
    const float* Y  = (const float*)d_in[1];
    const int*   xl = (const int*)d_in[2];
    const int*   yl = (const int*)d_in[3];
    float* out = (float*)d_out;
    uint32* Dsk = (uint32*)d_ws;   // 32 b * 4 strips * 4 J * 64 KB = 32 MB

    init_kernel<<<1, 512, 0, stream>>>();
    fused_kernel<<<544, 256, 0, stream>>>(X, Y, Dsk, xl, yl, out);
}

// Round 5
// 222.805 us; speedup vs baseline: 1.2260x; 1.2260x over previous
//
#include <hip/hip_runtime.h>
#include <hip/hip_fp16.h>
#include <cstddef>

#define Bc   32
#define Nc   512
#define Mc   512
#define DFc  64
#define BIGC 1.0e10f
#define LOG2E_F 1.4426950408889634f
#define LN2_F   0.6931471805599453f
#define SQRT_LOG2E_F 1.2011224087864498f

// new Dsk layout: per batch, slot (s, i) at ((s*64)+i)*32 bytes holds
// rows 8i+1..8i+8 (DP), cols 2c+1, 2c+2 with c = s - i, as 8 uint32 words
// (word r = fp16 O | fp16 E << 16). s in [0, 319) -> 653312 B per batch.
#define BSTRIDE 653312

typedef unsigned int uint32;
typedef _Float16 f16x8 __attribute__((ext_vector_type(8)));
typedef float    f32x4 __attribute__((ext_vector_type(4)));

__device__ __forceinline__ float dpp_shr1(float oldv, float src) {
    return __int_as_float(__builtin_amdgcn_update_dpp(
        __float_as_int(oldv), __float_as_int(src), 0x138, 0xf, 0xf, false));
}
__device__ __forceinline__ float rl(float v, int lane) {
    return __int_as_float(__builtin_amdgcn_readlane(__float_as_int(v), lane));
}

// Bit-trick softmin, log2 domain, minus 127 (bias pre-folded into Dsk).
// v_cvt_u32_f32 saturates negative inputs to 0 (= exp underflow), so any
// ~1e10 operand behaves bit-identically to an exact BIG border.
__device__ __forceinline__ float softmin3m(float a, float b, float c) {
    float mn = fminf(fminf(a, b), c);
    float mx = fmaxf(fmaxf(a, b), c);
    float md = __builtin_amdgcn_fmed3f(a, b, c);
    uint32 b1 = (uint32)fmaf(mn - mx, 8388608.0f, 1065353216.0f);
    uint32 b2 = (uint32)fmaf(mn - md, 8388608.0f, 1065353216.0f);
    float E = 1.0f + (__int_as_float(b1) + __int_as_float(b2));
    return fmaf((float)__float_as_uint(E), -1.1920929e-7f, mn);
}

// ---------------------------------------------------------------------------
// Kernel 1: MFMA distance computation (staging + MFMA unchanged).
// New epilogue: fp16 D into LDS P2[col][136-padded rows]; new output stage
// writes the [s][lane] diagonal-slot layout for the 8-row scan.
// ---------------------------------------------------------------------------
__global__ __launch_bounds__(256) void dist_kernel(
    const float* __restrict__ X, const float* __restrict__ Y,
    uint32* __restrict__ Dsk)
{
    __shared__ __align__(16) unsigned char SMEM[35840];
    unsigned short* XsH = (unsigned short*)SMEM;            // 16384 B
    unsigned short* YsH = (unsigned short*)(SMEM + 16384);  // 16384 B
    unsigned short* P2 = (unsigned short*)SMEM;             // 128x136 halves = 34816 B
    float* xx2 = (float*)(SMEM + 34816);                    // 512 B (survives P2)
    float* yy2 = (float*)(SMEM + 35328);                    // 512 B

    const int b     = blockIdx.z;
    const int strip = blockIdx.y;
    const int J     = blockIdx.x;
    const int tid   = threadIdx.x;

    const float* Xg = X + ((size_t)b * Nc + strip * 128) * DFc;
    const float* Yg = Y + ((size_t)b * Mc + J * 128) * DFc;

#pragma unroll
    for (int it = 0; it < 8; ++it) {
        int e4 = it * 256 + tid;
        int n = e4 >> 4, k4 = (e4 & 15) * 4;
        float4 v = ((const float4*)Xg)[e4];
        float sx = v.x * SQRT_LOG2E_F, sy = v.y * SQRT_LOG2E_F;
        float sz = v.z * SQRT_LOG2E_F, sw = v.w * SQRT_LOG2E_F;
        __half2 h01 = __floats2half2_rn(sx, sy);
        __half2 h23 = __floats2half2_rn(sz, sw);
        int ho = (k4 + 8 * (n & 7)) & 63;
        uint2 u; u.x = *(uint32*)&h01; u.y = *(uint32*)&h23;
        *(uint2*)&XsH[n * 64 + ho] = u;
        float p = sx * sx + sy * sy + sz * sz + sw * sw;
        p += __shfl_xor(p, 1);
        p += __shfl_xor(p, 2);
        p += __shfl_xor(p, 4);
        p += __shfl_xor(p, 8);
        if ((tid & 15) == 0) xx2[n] = p + 127.0f;   // fold the +127 bias here
    }
#pragma unroll
    for (int it = 0; it < 8; ++it) {
        int e4 = it * 256 + tid;
        int m = e4 >> 4, k4 = (e4 & 15) * 4;
        float4 v = ((const float4*)Yg)[e4];
        float sx = v.x * SQRT_LOG2E_F, sy = v.y * SQRT_LOG2E_F;
        float sz = v.z * SQRT_LOG2E_F, sw = v.w * SQRT_LOG2E_F;
        __half2 h01 = __floats2half2_rn(sx, sy);
        __half2 h23 = __floats2half2_rn(sz, sw);
        int ho = (k4 + 8 * (m & 7)) & 63;
        uint2 u; u.x = *(uint32*)&h01; u.y = *(uint32*)&h23;
        *(uint2*)&YsH[m * 64 + ho] = u;
        float p = sx * sx + sy * sy + sz * sz + sw * sw;
        p += __shfl_xor(p, 1);
        p += __shfl_xor(p, 2);
        p += __shfl_xor(p, 4);
        p += __shfl_xor(p, 8);
        if ((tid & 15) == 0) yy2[m] = p;
    }
    __syncthreads();

    const int l  = tid & 63;
    const int w  = tid >> 6;     // wave 0..3: rows [32w, 32w+32)
    const int lr = l & 15;       // fragment row/col
    const int lk = l >> 4;       // fragment k-group

    f32x4 acc[2][8];
#pragma unroll
    for (int rt = 0; rt < 2; ++rt)
#pragma unroll
        for (int ct = 0; ct < 8; ++ct) {
            f32x4 z = {0.f, 0.f, 0.f, 0.f};
            acc[rt][ct] = z;
        }

#pragma unroll
    for (int ks = 0; ks < 2; ++ks) {
        f16x8 af[2], bf[8];
#pragma unroll
        for (int rt = 0; rt < 2; ++rt) {
            int row = w * 32 + rt * 16 + lr;
            int ho = (ks * 32 + lk * 8 + 8 * (row & 7)) & 63;
            af[rt] = *(const f16x8*)&XsH[row * 64 + ho];
        }
#pragma unroll
        for (int ct = 0; ct < 8; ++ct) {
            int col = ct * 16 + lr;
            int ho = (ks * 32 + lk * 8 + 8 * (col & 7)) & 63;
            bf[ct] = *(const f16x8*)&YsH[col * 64 + ho];
        }
#pragma unroll
        for (int rt = 0; rt < 2; ++rt)
#pragma unroll
            for (int ct = 0; ct < 8; ++ct)
                acc[rt][ct] = __builtin_amdgcn_mfma_f32_16x16x32_f16(
                    af[rt], bf[ct], acc[rt][ct], 0, 0, 0);
    }
    __syncthreads();   // Xs/Ys dead; P2 may now overwrite them

    // ---- epilogue: D = xx2[row] + yy2[col] - 2*S -> fp16 P2[col][row] ----
    // C/D layout: col = l&15 (+16*ct), rows = w*32 + rt*16 + 4*lk + reg.
    // (d0,d1),(d2,d3) are consecutive rows -> one ds_write_b64 per (rt,ct).
#pragma unroll
    for (int rt = 0; rt < 2; ++rt) {
        int rbase = w * 32 + rt * 16 + 4 * lk;
        f32x4 xr = *(const f32x4*)&xx2[rbase];
#pragma unroll
        for (int ct = 0; ct < 8; ++ct) {
            int c = ct * 16 + lr;
            float yv = yy2[c];
            f32x4 a = acc[rt][ct];
            float d0 = xr[0] + yv - 2.0f * a[0];
            float d1 = xr[1] + yv - 2.0f * a[1];
            float d2 = xr[2] + yv - 2.0f * a[2];
            float d3 = xr[3] + yv - 2.0f * a[3];
            __half2 h0 = __floats2half2_rn(d0, d1);
            __half2 h1 = __floats2half2_rn(d2, d3);
            uint2 u; u.x = *(uint32*)&h0; u.y = *(uint32*)&h1;
            *(uint2*)&P2[c * 136 + rbase] = u;
        }
    }
    __syncthreads();

    // ---- output stage: write diagonal slots [s][i] (32 B each) ----
    // slot (a, cl): i = 16*strip + a, c = 64*J + cl; rows 8a..8a+7,
    // cols 2cl (O) and 2cl+1 (E); word r = O_r | E_r<<16.
    char* ob = (char*)Dsk + (size_t)b * BSTRIDE;
#pragma unroll
    for (int k = 0; k < 4; ++k) {
        int slot = k * 256 + tid;
        int a  = slot >> 6;
        int cl = slot & 63;
        int ii = 16 * strip + a;
        int cc = 64 * J + cl;
        uint4 r0 = *(const uint4*)&P2[(2 * cl) * 136 + 8 * a];
        uint4 r1 = *(const uint4*)&P2[(2 * cl + 1) * 136 + 8 * a];
        uint4 w0, w1;
        w0.x = (r0.x & 0xffffu) | (r1.x << 16);
        w0.y = (r0.x >> 16)     | (r1.x & 0xffff0000u);
        w0.z = (r0.y & 0xffffu) | (r1.y << 16);
        w0.w = (r0.y >> 16)     | (r1.y & 0xffff0000u);
        w1.x = (r0.z & 0xffffu) | (r1.z << 16);
        w1.y = (r0.z >> 16)     | (r1.z & 0xffff0000u);
        w1.z = (r0.w & 0xffffu) | (r1.w << 16);
        w1.w = (r0.w >> 16)     | (r1.w & 0xffff0000u);
        char* dst = ob + ((size_t)(cc + ii) * 64 + ii) * 32;
        *(uint4*)dst = w0;
        *(uint4*)(dst + 16) = w1;
    }
}

// ---------------------------------------------------------------------------
// Kernel 2: single-wave 8-row/lane diagonal scan. One wave per batch, no LDS,
// no barriers, no activation masking (free-running lanes on clamped-finite
// data stay ~1e10 and underflow identically to true BIG borders -> per-cell
// math bit-identical to the masked recurrence). 319-step wavefront, early
// exit at scap. Ring prefetch depth 4, static indices.
// ---------------------------------------------------------------------------
#define STEP8(JJ)                                                          \
  {                                                                        \
    float u1 = dpp_shr1(bigc, O7p);                                        \
    float u2 = dpp_shr1(bigc, E7p);                                        \
    float upO = u1, upE = u2;                                              \
    uint4 da = dregA[JJ], db = dregB[JJ];                                  \
    {                                                                      \
      int cc = s0 + ((JJ) + 4) - i;                                        \
      cc = min(max(cc, 0), 255);                                           \
      int vo = ((cc + i) << 11) + (i << 5);                                \
      dregA[JJ] = *(const uint4*)(tbase + vo);                             \
      dregB[JJ] = *(const uint4*)(tbase + vo + 16);                        \
    }                                                                      \
    const uint32 dw[8] = {da.x, da.y, da.z, da.w, db.x, db.y, db.z, db.w}; \
    _Pragma("unroll")                                                      \
    for (int r = 0; r < 8; ++r) {                                          \
      float2 f = __half22float2(*(const __half2*)&dw[r]);                  \
      float O = softmin3m(diag[r], upO, curE[r]) + f.x;                    \
      float E = softmin3m(upO, upE, O) + f.y;                              \
      diag[r] = upE;                                                       \
      curE[r] = E;                                                         \
      Ov[r] = O; Ev[r] = E;                                                \
      upO = O; upE = E;                                                    \
    }                                                                      \
    O7p = Ov[7]; E7p = Ev[7];                                              \
    if (s0 + (JJ) == scap) {                                               \
      float vv = useE ? Ev[0] : Ov[0];                                     \
      _Pragma("unroll")                                                    \
      for (int r = 1; r < 8; ++r)                                          \
        vv = (rcap == r) ? (useE ? Ev[r] : Ov[r]) : vv;                    \
      capv = (i == icap) ? vv : capv;                                      \
    }                                                                      \
  }

__global__ __launch_bounds__(64) void scan_kernel(
    const uint32* __restrict__ Dsk,
    const int* __restrict__ X_len, const int* __restrict__ Y_len,
    float* __restrict__ out)
{
    const int i  = threadIdx.x;        // lane: DP rows 8i+1..8i+8
    const int bb = blockIdx.x;

    const int xl = X_len[bb], yl = Y_len[bb];
    const int icap = (xl - 1) >> 3;    // capture lane
    const int rcap = (xl - 1) & 7;     // capture row-in-lane
    const int ccap = (yl - 1) >> 1;    // capture col-pair
    const int useE = (yl - 1) & 1;     // even col -> E cell
    const int scap = ccap + icap;      // capture step (<= 318)

    const char* tbase = (const char*)Dsk + (size_t)bb * BSTRIDE;

    const float bigc = BIGC;
    float curE[8], diag[8], Ov[8], Ev[8];
#pragma unroll
    for (int r = 0; r < 8; ++r) { curE[r] = BIGC; diag[r] = BIGC; }
    diag[0] = (i == 0) ? 0.0f : BIGC;      // R[0][0] seed
    float O7p = BIGC, E7p = BIGC, capv = 0.0f;

    // prologue: ring prefetch steps 0..3 (clamped -> always finite data)
    uint4 dregA[4], dregB[4];
#pragma unroll
    for (int j = 0; j < 4; ++j) {
        int cc = min(max(j - i, 0), 255);
        int vo = ((cc + i) << 11) + (i << 5);
        dregA[j] = *(const uint4*)(tbase + vo);
        dregB[j] = *(const uint4*)(tbase + vo + 16);
    }

#pragma unroll 1
    for (int s0 = 0; s0 <= scap; s0 += 4) {
        STEP8(0)
        STEP8(1)
        STEP8(2)
        STEP8(3)
    }

    float o = rl(capv, icap);
    if (i == 0) out[bb] = o * LN2_F;
}

extern "C" void kernel_launch(void* const* d_in, const int* in_sizes, int n_in,
                              void* d_out, int out_size, void* d_ws, size_t ws_size,
                              hipStream_t stream)
{
    const float* X  = (const float*)d_in[0];
    const float* Y  = (const float*)d_in[1];
    const int*   xl = (const int*)d_in[2];
    const int*   yl = (const int*)d_in[3];
    float* out = (float*)d_out;
    uint32* Dsk = (uint32*)d_ws;   // 32 batches * 653312 B = 20.9 MB

    dist_kernel<<<dim3(4, 4, Bc), 256, 0, stream>>>(X, Y, Dsk);
    scan_kernel<<<Bc, 64, 0, stream>>>(Dsk, xl, yl, out);
}